// Round 1
// baseline (8150.894 us; speedup 1.0000x reference)
//
#include <hip/hip_runtime.h>
#include <math.h>

#define BLOCK 256

__device__ __forceinline__ float sigmoid_fast(float v) {
    // 1 / (1 + e^-v) via v_exp_f32 + v_rcp_f32 (rel err ~1e-6, threshold is 1.5e-2)
    return __builtin_amdgcn_rcpf(1.0f + __expf(-v));
}

__device__ __forceinline__ void ln_silu_64(float h[64], const float* __restrict__ g,
                                           const float* __restrict__ be) {
    float mu = 0.f;
#pragma unroll
    for (int i = 0; i < 64; ++i) mu += h[i];
    mu *= (1.0f / 64.0f);
    float var = 0.f;
#pragma unroll
    for (int i = 0; i < 64; ++i) { float d = h[i] - mu; var = fmaf(d, d, var); }
    var *= (1.0f / 64.0f);
    float inv = __builtin_amdgcn_rsqf(var + 1e-5f);
#pragma unroll
    for (int i = 0; i < 64; ++i) {
        float v = (h[i] - mu) * inv * g[i] + be[i];
        h[i] = v * sigmoid_fast(v);
    }
}

__global__ __launch_bounds__(BLOCK) void mlp_fused_kernel(
    const float* __restrict__ x,
    const float* __restrict__ w1, const float* __restrict__ b1,
    const float* __restrict__ g1, const float* __restrict__ be1,
    const float* __restrict__ w2, const float* __restrict__ b2,
    const float* __restrict__ g2, const float* __restrict__ be2,
    const float* __restrict__ w3, const float* __restrict__ b3,
    const float* __restrict__ g3, const float* __restrict__ be3,
    float* __restrict__ out, int B)
{
    // Weights staged once per block in LDS; all per-row reads are wave-uniform
    // broadcasts (conflict-free).
    __shared__ float sW1[64 * 24];
    __shared__ float sW2[64 * 64];
    __shared__ float sW3[7 * 64];
    __shared__ float sB1[64], sG1[64], sBe1[64];
    __shared__ float sB2[64], sG2[64], sBe2[64];
    __shared__ float sB3[7], sG3[7], sBe3[7];

    const int tid = threadIdx.x;
    for (int i = tid; i < 64 * 24; i += BLOCK) sW1[i] = w1[i];
    for (int i = tid; i < 64 * 64; i += BLOCK) sW2[i] = w2[i];
    for (int i = tid; i < 7 * 64;  i += BLOCK) sW3[i] = w3[i];
    if (tid < 64) {
        sB1[tid] = b1[tid]; sG1[tid] = g1[tid]; sBe1[tid] = be1[tid];
        sB2[tid] = b2[tid]; sG2[tid] = g2[tid]; sBe2[tid] = be2[tid];
    }
    if (tid < 7) { sB3[tid] = b3[tid]; sG3[tid] = g3[tid]; sBe3[tid] = be3[tid]; }
    __syncthreads();

    const int stride = gridDim.x * BLOCK;
    for (int row = blockIdx.x * BLOCK + tid; row < B; row += stride) {
        // ---- load x row: 24 floats = 6x float4 (row*96B is 16B-aligned) ----
        float xr[24];
        const float4* xp = (const float4*)(x + (size_t)row * 24);
#pragma unroll
        for (int i = 0; i < 6; ++i) {
            float4 v = xp[i];
            xr[i * 4 + 0] = v.x; xr[i * 4 + 1] = v.y;
            xr[i * 4 + 2] = v.z; xr[i * 4 + 3] = v.w;
        }

        // ---- layer 1: [24] -> [64], + bias, LN, SiLU ----
        float h1[64];
#pragma unroll
        for (int o = 0; o < 64; ++o) {
            const float4* wp = (const float4*)(sW1 + o * 24);  // 96B-aligned
            float a0 = 0.f, a1 = 0.f, a2 = 0.f, a3 = 0.f;
#pragma unroll
            for (int k = 0; k < 6; ++k) {
                float4 w = wp[k];
                a0 = fmaf(xr[k * 4 + 0], w.x, a0);
                a1 = fmaf(xr[k * 4 + 1], w.y, a1);
                a2 = fmaf(xr[k * 4 + 2], w.z, a2);
                a3 = fmaf(xr[k * 4 + 3], w.w, a3);
            }
            h1[o] = sB1[o] + ((a0 + a1) + (a2 + a3));
        }
        ln_silu_64(h1, sG1, sBe1);

        // ---- layer 2: [64] -> [64], + bias, LN, SiLU ----
        float h2[64];
#pragma unroll
        for (int o = 0; o < 64; ++o) {
            const float4* wp = (const float4*)(sW2 + o * 64);  // 256B-aligned
            float a0 = 0.f, a1 = 0.f, a2 = 0.f, a3 = 0.f;
#pragma unroll
            for (int k = 0; k < 16; ++k) {
                float4 w = wp[k];
                a0 = fmaf(h1[k * 4 + 0], w.x, a0);
                a1 = fmaf(h1[k * 4 + 1], w.y, a1);
                a2 = fmaf(h1[k * 4 + 2], w.z, a2);
                a3 = fmaf(h1[k * 4 + 3], w.w, a3);
            }
            h2[o] = sB2[o] + ((a0 + a1) + (a2 + a3));
        }
        ln_silu_64(h2, sG2, sBe2);

        // ---- layer 3: [64] -> [7], + bias, LN, softmax ----
        float h3[7];
#pragma unroll
        for (int o = 0; o < 7; ++o) {
            const float4* wp = (const float4*)(sW3 + o * 64);
            float a0 = 0.f, a1 = 0.f, a2 = 0.f, a3 = 0.f;
#pragma unroll
            for (int k = 0; k < 16; ++k) {
                float4 w = wp[k];
                a0 = fmaf(h2[k * 4 + 0], w.x, a0);
                a1 = fmaf(h2[k * 4 + 1], w.y, a1);
                a2 = fmaf(h2[k * 4 + 2], w.z, a2);
                a3 = fmaf(h2[k * 4 + 3], w.w, a3);
            }
            h3[o] = sB3[o] + ((a0 + a1) + (a2 + a3));
        }

        float mu = 0.f;
#pragma unroll
        for (int j = 0; j < 7; ++j) mu += h3[j];
        mu *= (1.0f / 7.0f);
        float var = 0.f;
#pragma unroll
        for (int j = 0; j < 7; ++j) { float d = h3[j] - mu; var = fmaf(d, d, var); }
        var *= (1.0f / 7.0f);
        float inv = __builtin_amdgcn_rsqf(var + 1e-5f);

        float m = -1e30f;
#pragma unroll
        for (int j = 0; j < 7; ++j) {
            float v = (h3[j] - mu) * inv * sG3[j] + sBe3[j];
            h3[j] = v;
            m = fmaxf(m, v);
        }
        float s = 0.f;
#pragma unroll
        for (int j = 0; j < 7; ++j) { float e = __expf(h3[j] - m); h3[j] = e; s += e; }
        float r = __builtin_amdgcn_rcpf(s);

        float* op = out + (size_t)row * 7;
#pragma unroll
        for (int j = 0; j < 7; ++j) op[j] = h3[j] * r;
    }
}

extern "C" void kernel_launch(void* const* d_in, const int* in_sizes, int n_in,
                              void* d_out, int out_size, void* d_ws, size_t ws_size,
                              hipStream_t stream) {
    const float* x   = (const float*)d_in[0];
    const float* w1  = (const float*)d_in[1];
    const float* b1  = (const float*)d_in[2];
    const float* g1  = (const float*)d_in[3];
    const float* be1 = (const float*)d_in[4];
    const float* w2  = (const float*)d_in[5];
    const float* b2  = (const float*)d_in[6];
    const float* g2  = (const float*)d_in[7];
    const float* be2 = (const float*)d_in[8];
    const float* w3  = (const float*)d_in[9];
    const float* b3  = (const float*)d_in[10];
    const float* g3  = (const float*)d_in[11];
    const float* be3 = (const float*)d_in[12];
    float* out = (float*)d_out;

    const int B = in_sizes[0] / 24;
    const int blocks = (B + BLOCK - 1) / BLOCK;
    hipLaunchKernelGGL(mlp_fused_kernel, dim3(blocks), dim3(BLOCK), 0, stream,
                       x, w1, b1, g1, be1, w2, b2, g2, be2, w3, b3, g3, be3,
                       out, B);
}

// Round 2
// 2519.809 us; speedup vs baseline: 3.2347x; 3.2347x over previous
//
#include <hip/hip_runtime.h>
#include <math.h>

#define BLOCK 256

__device__ __forceinline__ float sigmoid_fast(float v) {
    return __builtin_amdgcn_rcpf(1.0f + __expf(-v));
}

// LN + SiLU over 64 in-register values; g/be read via uniform (SGPR) loads.
__device__ __forceinline__ void ln_silu_64(float h[64], const float* __restrict__ g,
                                           const float* __restrict__ be) {
    float mu = 0.f;
#pragma unroll
    for (int i = 0; i < 64; ++i) mu += h[i];
    mu *= (1.0f / 64.0f);
    float var = 0.f;
#pragma unroll
    for (int i = 0; i < 64; ++i) { float d = h[i] - mu; var = fmaf(d, d, var); }
    var *= (1.0f / 64.0f);
    float inv = __builtin_amdgcn_rsqf(var + 1e-5f);
#pragma unroll
    for (int i = 0; i < 64; ++i) {
        float v = (h[i] - mu) * inv * g[i] + be[i];   // g[i]/be[i]: uniform -> s_load
        h[i] = v * sigmoid_fast(v);
    }
}

__global__ __launch_bounds__(BLOCK) void mlp_fused_kernel(
    const float* __restrict__ x,
    const float* __restrict__ w1, const float* __restrict__ b1,
    const float* __restrict__ g1, const float* __restrict__ be1,
    const float* __restrict__ w2, const float* __restrict__ b2,
    const float* __restrict__ g2, const float* __restrict__ be2,
    const float* __restrict__ w3, const float* __restrict__ b3,
    const float* __restrict__ g3, const float* __restrict__ be3,
    float* __restrict__ out, int B)
{
    // NO LDS for weights: all weight indices are compile-time constants and the
    // pointers are kernel args, so every weight access is wave-uniform ->
    // compiler emits s_load -> SGPR operand in v_fma (zero VGPR cost, zero
    // ds_read). Per-thread VGPR live set is just xr/h1/h2 (~140) -> no spill.
    const int tid = threadIdx.x;
    const int stride = gridDim.x * BLOCK;
    for (int row = blockIdx.x * BLOCK + tid; row < B; row += stride) {
        // ---- load x row: 24 floats = 6x float4 (96B row, 16B aligned) ----
        float xr[24];
        const float4* xp = (const float4*)(x + (size_t)row * 24);
#pragma unroll
        for (int i = 0; i < 6; ++i) {
            float4 v = xp[i];
            xr[i * 4 + 0] = v.x; xr[i * 4 + 1] = v.y;
            xr[i * 4 + 2] = v.z; xr[i * 4 + 3] = v.w;
        }

        // ---- layer 1: [24] -> [64], + bias, LN, SiLU ----
        float h1[64];
#pragma unroll
        for (int o = 0; o < 64; ++o) {
            float a0 = b1[o], a1 = 0.f, a2 = 0.f, a3 = 0.f;
#pragma unroll
            for (int k = 0; k < 6; ++k) {
                a0 = fmaf(xr[k * 4 + 0], w1[o * 24 + k * 4 + 0], a0);
                a1 = fmaf(xr[k * 4 + 1], w1[o * 24 + k * 4 + 1], a1);
                a2 = fmaf(xr[k * 4 + 2], w1[o * 24 + k * 4 + 2], a2);
                a3 = fmaf(xr[k * 4 + 3], w1[o * 24 + k * 4 + 3], a3);
            }
            h1[o] = (a0 + a1) + (a2 + a3);
        }
        ln_silu_64(h1, g1, be1);

        // ---- layer 2: [64] -> [64], + bias, LN, SiLU ----
        float h2[64];
#pragma unroll
        for (int o = 0; o < 64; ++o) {
            float a0 = b2[o], a1 = 0.f, a2 = 0.f, a3 = 0.f;
#pragma unroll
            for (int k = 0; k < 16; ++k) {
                a0 = fmaf(h1[k * 4 + 0], w2[o * 64 + k * 4 + 0], a0);
                a1 = fmaf(h1[k * 4 + 1], w2[o * 64 + k * 4 + 1], a1);
                a2 = fmaf(h1[k * 4 + 2], w2[o * 64 + k * 4 + 2], a2);
                a3 = fmaf(h1[k * 4 + 3], w2[o * 64 + k * 4 + 3], a3);
            }
            h2[o] = (a0 + a1) + (a2 + a3);
        }
        ln_silu_64(h2, g2, be2);

        // ---- layer 3: [64] -> [7], + bias, LN, softmax ----
        float h3[7];
#pragma unroll
        for (int o = 0; o < 7; ++o) {
            float a0 = b3[o], a1 = 0.f, a2 = 0.f, a3 = 0.f;
#pragma unroll
            for (int k = 0; k < 16; ++k) {
                a0 = fmaf(h2[k * 4 + 0], w3[o * 64 + k * 4 + 0], a0);
                a1 = fmaf(h2[k * 4 + 1], w3[o * 64 + k * 4 + 1], a1);
                a2 = fmaf(h2[k * 4 + 2], w3[o * 64 + k * 4 + 2], a2);
                a3 = fmaf(h2[k * 4 + 3], w3[o * 64 + k * 4 + 3], a3);
            }
            h3[o] = (a0 + a1) + (a2 + a3);
        }

        float mu = 0.f;
#pragma unroll
        for (int j = 0; j < 7; ++j) mu += h3[j];
        mu *= (1.0f / 7.0f);
        float var = 0.f;
#pragma unroll
        for (int j = 0; j < 7; ++j) { float d = h3[j] - mu; var = fmaf(d, d, var); }
        var *= (1.0f / 7.0f);
        float inv = __builtin_amdgcn_rsqf(var + 1e-5f);

        float m = -1e30f;
#pragma unroll
        for (int j = 0; j < 7; ++j) {
            float v = (h3[j] - mu) * inv * g3[j] + be3[j];
            h3[j] = v;
            m = fmaxf(m, v);
        }
        float s = 0.f;
#pragma unroll
        for (int j = 0; j < 7; ++j) { float e = __expf(h3[j] - m); h3[j] = e; s += e; }
        float r = __builtin_amdgcn_rcpf(s);

        float* op = out + (size_t)row * 7;
#pragma unroll
        for (int j = 0; j < 7; ++j) op[j] = h3[j] * r;
    }
}

extern "C" void kernel_launch(void* const* d_in, const int* in_sizes, int n_in,
                              void* d_out, int out_size, void* d_ws, size_t ws_size,
                              hipStream_t stream) {
    const float* x   = (const float*)d_in[0];
    const float* w1  = (const float*)d_in[1];
    const float* b1  = (const float*)d_in[2];
    const float* g1  = (const float*)d_in[3];
    const float* be1 = (const float*)d_in[4];
    const float* w2  = (const float*)d_in[5];
    const float* b2  = (const float*)d_in[6];
    const float* g2  = (const float*)d_in[7];
    const float* be2 = (const float*)d_in[8];
    const float* w3  = (const float*)d_in[9];
    const float* b3  = (const float*)d_in[10];
    const float* g3  = (const float*)d_in[11];
    const float* be3 = (const float*)d_in[12];
    float* out = (float*)d_out;

    const int B = in_sizes[0] / 24;
    const int blocks = (B + BLOCK - 1) / BLOCK;
    hipLaunchKernelGGL(mlp_fused_kernel, dim3(blocks), dim3(BLOCK), 0, stream,
                       x, w1, b1, g1, be1, w2, b2, g2, be2, w3, b3, g3, be3,
                       out, B);
}

// Round 4
// 220.831 us; speedup vs baseline: 36.9101x; 11.4106x over previous
//
#include <hip/hip_runtime.h>
#include <math.h>

#define BLOCK 256
#define WPB 4            // waves per block
#define NBLOCKS 2048

typedef float  f32x4 __attribute__((ext_vector_type(4)));
typedef float  f32x2 __attribute__((ext_vector_type(2)));
typedef short  short8 __attribute__((ext_vector_type(8)));   // 8 bf16 = MFMA A/B frag
typedef unsigned int u32;
typedef u32 u32x4 __attribute__((ext_vector_type(4)));
typedef u32 u32x2 __attribute__((ext_vector_type(2)));

// D = A[16x32] * B[32x16] + C, bf16 inputs, fp32 accum.
// A: lane holds row (lane&15), k = (lane>>4)*8 .. +8
// B: lane holds col (lane&15), k = (lane>>4)*8 .. +8
// D: lane holds col (lane&15), row = (lane>>4)*4 + reg   [measured: m89]
static __device__ __forceinline__ f32x4 mfma16(short8 a, short8 b, f32x4 c) {
    return __builtin_amdgcn_mfma_f32_16x16x32_bf16(a, b, c, 0, 0, 0);
}

static __device__ __forceinline__ u32 cvt_pk(float lo, float hi) {
    u32 r;
    asm("v_cvt_pk_bf16_f32 %0, %1, %2" : "=v"(r) : "v"(lo), "v"(hi));
    return r;  // low half = bf16(lo), high half = bf16(hi)
}
static __device__ __forceinline__ float unpk_lo(u32 p) { return __builtin_bit_cast(float, p << 16); }
static __device__ __forceinline__ float unpk_hi(u32 p) { return __builtin_bit_cast(float, p & 0xffff0000u); }

static __device__ __forceinline__ short8 mk_frag(u32 a, u32 b, u32 c, u32 d) {
    u32x4 t = {a, b, c, d};
    return __builtin_bit_cast(short8, t);
}

struct Frag2 { short8 hi, lo; };

// 8 f32 -> hi frag (bf16 RNE) + lo frag (bf16 of exact residual): ~17-bit mantissa total
static __device__ __forceinline__ Frag2 split8(f32x4 a, f32x4 b) {
    u32 h0 = cvt_pk(a[0], a[1]), h1 = cvt_pk(a[2], a[3]);
    u32 h2 = cvt_pk(b[0], b[1]), h3 = cvt_pk(b[2], b[3]);
    u32 l0 = cvt_pk(a[0] - unpk_lo(h0), a[1] - unpk_hi(h0));
    u32 l1 = cvt_pk(a[2] - unpk_lo(h1), a[3] - unpk_hi(h1));
    u32 l2 = cvt_pk(b[0] - unpk_lo(h2), b[1] - unpk_hi(h2));
    u32 l3 = cvt_pk(b[2] - unpk_lo(h3), b[3] - unpk_hi(h3));
    Frag2 r; r.hi = mk_frag(h0, h1, h2, h3); r.lo = mk_frag(l0, l1, l2, l3);
    return r;
}

// 4 f32 -> packed bf16 hi pair + lo pair (for LDS staging)
static __device__ __forceinline__ void split4(f32x4 v, u32x2& hi, u32x2& lo) {
    u32 h0 = cvt_pk(v[0], v[1]), h1 = cvt_pk(v[2], v[3]);
    u32 l0 = cvt_pk(v[0] - unpk_lo(h0), v[1] - unpk_hi(h0));
    u32 l1 = cvt_pk(v[2] - unpk_lo(h1), v[3] - unpk_hi(h1));
    hi = u32x2{h0, h1}; lo = u32x2{l0, l1};
}

static __device__ __forceinline__ Frag2 wfrag(const float* p) {
    return split8(*(const f32x4*)p, *(const f32x4*)(p + 4));
}

static __device__ __forceinline__ float red4(float v) {  // sum across the 4 k-groups
    v += __shfl_xor(v, 16);
    v += __shfl_xor(v, 32);
    return v;
}
static __device__ __forceinline__ float redmax4(float v) {
    v = fmaxf(v, __shfl_xor(v, 16));
    v = fmaxf(v, __shfl_xor(v, 32));
    return v;
}

__global__ __launch_bounds__(BLOCK, 2) void mlp_mfma_kernel(
    const float* __restrict__ x,
    const float* __restrict__ w1, const float* __restrict__ b1,
    const float* __restrict__ g1, const float* __restrict__ be1,
    const float* __restrict__ w2, const float* __restrict__ b2,
    const float* __restrict__ g2, const float* __restrict__ be2,
    const float* __restrict__ w3, const float* __restrict__ b3,
    const float* __restrict__ g3, const float* __restrict__ be3,
    float* __restrict__ out, int ntiles)
{
    // Per-wave: 2048B hi strip + 2048B lo strip (XOR-swizzled) + 768B out repack.
    __shared__ __align__(16) unsigned char smem[WPB * 4096 + WPB * 768];
    // LN params, block-shared: B1,G1,Be1,B2,G2,Be2 (64 each), B3,G3,Be3 (16 each, 0-padded)
    __shared__ __align__(16) float sP[6 * 64 + 3 * 16];

    const int tid = threadIdx.x;
    const int lane = tid & 63;
    const int wib  = tid >> 6;
    const int c = lane & 15;   // batch col within tile
    const int q = lane >> 4;   // k-group (8 elems each)

    if (tid < 64) {
        sP[        tid] = b1[tid];  sP[ 64 + tid] = g1[tid];  sP[128 + tid] = be1[tid];
        sP[192 + tid] = b2[tid];    sP[256 + tid] = g2[tid];  sP[320 + tid] = be2[tid];
    }
    if (tid < 16) {
        const bool ok = tid < 7;
        sP[384 + tid] = ok ? b3[tid]  : 0.f;
        sP[400 + tid] = ok ? g3[tid]  : 0.f;
        sP[416 + tid] = ok ? be3[tid] : 0.f;
    }

    unsigned char* sHi   = smem + wib * 4096;
    unsigned char* sLo   = sHi + 2048;
    unsigned char* obase = smem + WPB * 4096 + wib * 768;

    const u32 crow = (u32)c * 128u;
    const u32 ch   = (u32)(c & 7);

    const f32x4 z4 = {0.f, 0.f, 0.f, 0.f};

    // ---- preload weight hi/lo frags ----
    Frag2 w1f[4];              // W1[64,24] pad K->32; k=24 column carries b1 (bias fold)
#pragma unroll
    for (int mt = 0; mt < 4; ++mt) {
        if (q < 3) {
            w1f[mt] = wfrag(w1 + (mt * 16 + c) * 24 + q * 8);
        } else {
            float s = b1[mt * 16 + c];
            f32x4 a = {s, 0.f, 0.f, 0.f};
            w1f[mt] = split8(a, z4);
        }
    }
    Frag2 w2f[4][2];           // W2[64,64]
#pragma unroll
    for (int mt = 0; mt < 4; ++mt)
#pragma unroll
        for (int kk = 0; kk < 2; ++kk)
            w2f[mt][kk] = wfrag(w2 + (mt * 16 + c) * 64 + kk * 32 + q * 8);
    Frag2 w3f[2];              // W3[7,64]: rows c<7 valid, rest zero
#pragma unroll
    for (int kk = 0; kk < 2; ++kk) {
        if (c < 7) w3f[kk] = wfrag(w3 + c * 64 + kk * 32 + q * 8);
        else       w3f[kk] = split8(z4, z4);
    }

    __syncthreads();   // sP ready

    // output repack lane mapping
    const int c0 = lane / 7, f0 = lane - c0 * 7;
    const int i1 = lane + 64;
    const int c1 = i1 / 7, f1 = i1 - c1 * 7;

    const int wid = blockIdx.x * WPB + wib;
    const int tstride = gridDim.x * WPB;

    // ---- prefetch first tile's x; q==3 lanes carry the constant-1 bias slot ----
    f32x4 xa = z4, xb = z4;
    int tile = wid;
    if (tile < ntiles && q < 3) {
        const float* xp = x + ((size_t)tile * 16 + c) * 24 + q * 8;
        xa = *(const f32x4*)xp;
        xb = *(const f32x4*)(xp + 4);
    }
    if (q == 3) xa[0] = 1.0f;   // k=24 -> 1.0 (exact in bf16, lo=0)

    for (; tile < ntiles; tile += tstride) {
        // keep LDS param reads inside the loop (stop LICM re-hoisting -> VGPR blowup)
        asm volatile("" ::: "memory");

        Frag2 bx = split8(xa, xb);

        // prefetch next tile
        {
            const int nt = tile + tstride;
            if (nt < ntiles && q < 3) {
                const float* xp = x + ((size_t)nt * 16 + c) * 24 + q * 8;
                xa = *(const f32x4*)xp;
                xb = *(const f32x4*)(xp + 4);
            }
        }

        // ---- layer 1 (bias folded into k=24): 3-term compensated MFMA ----
        f32x4 d1[4];
#pragma unroll
        for (int mt = 0; mt < 4; ++mt) {
            f32x4 d = mfma16(w1f[mt].hi, bx.hi, z4);
            d = mfma16(w1f[mt].hi, bx.lo, d);
            d = mfma16(w1f[mt].lo, bx.hi, d);
            d1[mt] = d;
        }
        {
            float s = 0.f, s2 = 0.f;
#pragma unroll
            for (int mt = 0; mt < 4; ++mt)
#pragma unroll
                for (int r = 0; r < 4; ++r) {
                    float v = d1[mt][r];
                    s += v; s2 = fmaf(v, v, s2);
                }
            s = red4(s); s2 = red4(s2);
            const float mu = s * (1.f / 64.f);
            const float var = s2 * (1.f / 64.f) - mu * mu;
            const float inv = __builtin_amdgcn_rsqf(var + 1e-5f);
#pragma unroll
            for (int mt = 0; mt < 4; ++mt) {
                const f32x4 gv  = *(const f32x4*)(sP +  64 + mt * 16 + q * 4);
                const f32x4 bev = *(const f32x4*)(sP + 128 + mt * 16 + q * 4);
#pragma unroll
                for (int r = 0; r < 4; ++r) {
                    float t = (d1[mt][r] - mu) * inv;
                    float v = fmaf(t, gv[r], bev[r]);
                    d1[mt][r] = v * __builtin_amdgcn_rcpf(1.f + __expf(-v));
                }
            }
        }

        // ---- stage H1 (hi/lo strips, swizzled), read back as B-frags ----
#pragma unroll
        for (int mt = 0; mt < 4; ++mt) {
            u32x2 hi, lo;
            split4(d1[mt], hi, lo);
            u32 off = crow + ((((u32)(mt * 2 + (q >> 1))) ^ ch) << 4) + (u32)((q & 1) * 8);
            *(u32x2*)(sHi + off) = hi;
            *(u32x2*)(sLo + off) = lo;
        }
        short8 bhHi[2], bhLo[2];
#pragma unroll
        for (int kk = 0; kk < 2; ++kk) {
            u32 roff = crow + ((((u32)(kk * 4 + q)) ^ ch) << 4);
            bhHi[kk] = *(const short8*)(sHi + roff);
            bhLo[kk] = *(const short8*)(sLo + roff);
        }

        // ---- layer 2: 3-term compensated, K=64 ----
        f32x4 d2[4];
#pragma unroll
        for (int mt = 0; mt < 4; ++mt) {
            f32x4 d = mfma16(w2f[mt][0].hi, bhHi[0], z4);
            d = mfma16(w2f[mt][0].hi, bhLo[0], d);
            d = mfma16(w2f[mt][0].lo, bhHi[0], d);
            d = mfma16(w2f[mt][1].hi, bhHi[1], d);
            d = mfma16(w2f[mt][1].hi, bhLo[1], d);
            d = mfma16(w2f[mt][1].lo, bhHi[1], d);
            d2[mt] = d;
        }
        {
            float s = 0.f, s2 = 0.f;
#pragma unroll
            for (int mt = 0; mt < 4; ++mt) {
                const f32x4 bv = *(const f32x4*)(sP + 192 + mt * 16 + q * 4);
#pragma unroll
                for (int r = 0; r < 4; ++r) {
                    float v = d2[mt][r] + bv[r];
                    d2[mt][r] = v;
                    s += v; s2 = fmaf(v, v, s2);
                }
            }
            s = red4(s); s2 = red4(s2);
            const float mu = s * (1.f / 64.f);
            const float var = s2 * (1.f / 64.f) - mu * mu;
            const float inv = __builtin_amdgcn_rsqf(var + 1e-5f);
#pragma unroll
            for (int mt = 0; mt < 4; ++mt) {
                const f32x4 gv  = *(const f32x4*)(sP + 256 + mt * 16 + q * 4);
                const f32x4 bev = *(const f32x4*)(sP + 320 + mt * 16 + q * 4);
#pragma unroll
                for (int r = 0; r < 4; ++r) {
                    float t = (d2[mt][r] - mu) * inv;
                    float v = fmaf(t, gv[r], bev[r]);
                    d2[mt][r] = v * __builtin_amdgcn_rcpf(1.f + __expf(-v));
                }
            }
        }

        // ---- stage H2, read B-frags for layer 3 ----
#pragma unroll
        for (int mt = 0; mt < 4; ++mt) {
            u32x2 hi, lo;
            split4(d2[mt], hi, lo);
            u32 off = crow + ((((u32)(mt * 2 + (q >> 1))) ^ ch) << 4) + (u32)((q & 1) * 8);
            *(u32x2*)(sHi + off) = hi;
            *(u32x2*)(sLo + off) = lo;
        }
#pragma unroll
        for (int kk = 0; kk < 2; ++kk) {
            u32 roff = crow + ((((u32)(kk * 4 + q)) ^ ch) << 4);
            bhHi[kk] = *(const short8*)(sHi + roff);
            bhLo[kk] = *(const short8*)(sLo + roff);
        }

        // ---- layer 3: two 3-term chains summed (latency) ----
        f32x4 d3a = mfma16(w3f[0].hi, bhHi[0], z4);
        d3a = mfma16(w3f[0].hi, bhLo[0], d3a);
        d3a = mfma16(w3f[0].lo, bhHi[0], d3a);
        f32x4 d3b = mfma16(w3f[1].hi, bhHi[1], z4);
        d3b = mfma16(w3f[1].hi, bhLo[1], d3b);
        d3b = mfma16(w3f[1].lo, bhHi[1], d3b);
        f32x4 d3;
#pragma unroll
        for (int r = 0; r < 4; ++r) d3[r] = d3a[r] + d3b[r];

        // bias + LN(7) + softmax(7); valid features f = q*4+r < 7
        {
            const f32x4 b3v  = *(const f32x4*)(sP + 384 + q * 4);
            const f32x4 g3v  = *(const f32x4*)(sP + 400 + q * 4);
            const f32x4 be3v = *(const f32x4*)(sP + 416 + q * 4);
            float s = 0.f, s2 = 0.f;
#pragma unroll
            for (int r = 0; r < 4; ++r) {
                float v = d3[r] + b3v[r];
                d3[r] = v;
                const bool ok = (q * 4 + r) < 7;
                if (ok) { s += v; s2 = fmaf(v, v, s2); }
            }
            s = red4(s); s2 = red4(s2);
            const float mu = s * (1.f / 7.f);
            const float var = s2 * (1.f / 7.f) - mu * mu;
            const float inv = __builtin_amdgcn_rsqf(var + 1e-5f);

            float z[4]; float mx = -1e30f;
#pragma unroll
            for (int r = 0; r < 4; ++r) {
                z[r] = fmaf((d3[r] - mu) * inv, g3v[r], be3v[r]);
                const bool ok = (q * 4 + r) < 7;
                if (ok) mx = fmaxf(mx, z[r]);
            }
            mx = redmax4(mx);
            float es = 0.f; float e[4];
#pragma unroll
            for (int r = 0; r < 4; ++r) {
                const bool ok = (q * 4 + r) < 7;
                e[r] = ok ? __expf(z[r] - mx) : 0.f;
                es += e[r];
            }
            es = red4(es);
            const float rs = __builtin_amdgcn_rcpf(es);

            // repack via LDS (48B rows) -> coalesced stores
            if (q == 0) {
                f32x4 v = {e[0] * rs, e[1] * rs, e[2] * rs, e[3] * rs};
                *(f32x4*)(obase + c * 48) = v;
            } else if (q == 1) {
                f32x2 v = {e[0] * rs, e[1] * rs};
                *(f32x2*)(obase + c * 48 + 16) = v;
                *(float*)(obase + c * 48 + 24) = e[2] * rs;
            }
            float* outp = out + (size_t)tile * 112;
            float r0 = *(const float*)(obase + c0 * 48 + f0 * 4);
            outp[lane] = r0;
            if (lane < 48) {
                float r1 = *(const float*)(obase + c1 * 48 + f1 * 4);
                outp[64 + lane] = r1;
            }
        }
    }
}

extern "C" void kernel_launch(void* const* d_in, const int* in_sizes, int n_in,
                              void* d_out, int out_size, void* d_ws, size_t ws_size,
                              hipStream_t stream) {
    const float* x   = (const float*)d_in[0];
    const float* w1  = (const float*)d_in[1];
    const float* b1  = (const float*)d_in[2];
    const float* g1  = (const float*)d_in[3];
    const float* be1 = (const float*)d_in[4];
    const float* w2  = (const float*)d_in[5];
    const float* b2  = (const float*)d_in[6];
    const float* g2  = (const float*)d_in[7];
    const float* be2 = (const float*)d_in[8];
    const float* w3  = (const float*)d_in[9];
    const float* b3  = (const float*)d_in[10];
    const float* g3  = (const float*)d_in[11];
    const float* be3 = (const float*)d_in[12];
    float* out = (float*)d_out;

    const int B = in_sizes[0] / 24;
    const int ntiles = B / 16;   // B = 2^21 -> exact
    hipLaunchKernelGGL(mlp_mfma_kernel, dim3(NBLOCKS), dim3(BLOCK), 0, stream,
                       x, w1, b1, g1, be1, w2, b2, g2, be2, w3, b3, g3, be3,
                       out, ntiles);
}

// Round 5
// 200.655 us; speedup vs baseline: 40.6214x; 1.1005x over previous
//
#include <hip/hip_runtime.h>
#include <math.h>

#define BLOCK 256
#define WPB 4            // waves per block
#define NBLOCKS 2048

typedef float  f32x4 __attribute__((ext_vector_type(4)));
typedef float  f32x2 __attribute__((ext_vector_type(2)));
typedef short  short8 __attribute__((ext_vector_type(8)));   // 8 bf16 = MFMA A/B frag
typedef unsigned int u32;
typedef u32 u32x4 __attribute__((ext_vector_type(4)));
typedef u32 u32x2 __attribute__((ext_vector_type(2)));

// D = A[16x32] * B[32x16] + C, bf16 inputs, fp32 accum.
// A: lane holds row (lane&15), k = (lane>>4)*8 .. +8
// B: lane holds col (lane&15), k = (lane>>4)*8 .. +8
// D: lane holds col (lane&15), row = (lane>>4)*4 + reg   [measured: m89]
static __device__ __forceinline__ f32x4 mfma16(short8 a, short8 b, f32x4 c) {
    return __builtin_amdgcn_mfma_f32_16x16x32_bf16(a, b, c, 0, 0, 0);
}

static __device__ __forceinline__ f32x4 zero4() { f32x4 z = {0.f, 0.f, 0.f, 0.f}; return z; }

static __device__ __forceinline__ u32 cvt_pk(float lo, float hi) {
    u32 r;
    asm("v_cvt_pk_bf16_f32 %0, %1, %2" : "=v"(r) : "v"(lo), "v"(hi));
    return r;  // low half = bf16(lo), high half = bf16(hi)
}
static __device__ __forceinline__ float unpk_lo(u32 p) { return __builtin_bit_cast(float, p << 16); }
static __device__ __forceinline__ float unpk_hi(u32 p) { return __builtin_bit_cast(float, p & 0xffff0000u); }

static __device__ __forceinline__ short8 mk_frag(u32 a, u32 b, u32 c, u32 d) {
    u32x4 t = {a, b, c, d};
    return __builtin_bit_cast(short8, t);
}

struct Frag2 { short8 hi, lo; };

// 8 f32 -> hi frag (bf16 RNE) + lo frag (bf16 of exact residual): ~17-bit mantissa
static __device__ __forceinline__ Frag2 split8(f32x4 a, f32x4 b) {
    u32 h0 = cvt_pk(a[0], a[1]), h1 = cvt_pk(a[2], a[3]);
    u32 h2 = cvt_pk(b[0], b[1]), h3 = cvt_pk(b[2], b[3]);
    u32 l0 = cvt_pk(a[0] - unpk_lo(h0), a[1] - unpk_hi(h0));
    u32 l1 = cvt_pk(a[2] - unpk_lo(h1), a[3] - unpk_hi(h1));
    u32 l2 = cvt_pk(b[0] - unpk_lo(h2), b[1] - unpk_hi(h2));
    u32 l3 = cvt_pk(b[2] - unpk_lo(h3), b[3] - unpk_hi(h3));
    Frag2 r; r.hi = mk_frag(h0, h1, h2, h3); r.lo = mk_frag(l0, l1, l2, l3);
    return r;
}

static __device__ __forceinline__ void split4(f32x4 v, u32x2& hi, u32x2& lo) {
    u32 h0 = cvt_pk(v[0], v[1]), h1 = cvt_pk(v[2], v[3]);
    u32 l0 = cvt_pk(v[0] - unpk_lo(h0), v[1] - unpk_hi(h0));
    u32 l1 = cvt_pk(v[2] - unpk_lo(h1), v[3] - unpk_hi(h1));
    hi = u32x2{h0, h1}; lo = u32x2{l0, l1};
}

static __device__ __forceinline__ Frag2 wfrag(const float* p) {
    return split8(*(const f32x4*)p, *(const f32x4*)(p + 4));
}

static __device__ __forceinline__ float red4(float v) {  // sum across the 4 k-groups
    v += __shfl_xor(v, 16);
    v += __shfl_xor(v, 32);
    return v;
}
static __device__ __forceinline__ float redmax4(float v) {
    v = fmaxf(v, __shfl_xor(v, 16));
    v = fmaxf(v, __shfl_xor(v, 32));
    return v;
}

// --------- per-tile register state (all indices compile-time) ---------
struct TState {
    f32x4 xa, xb;            // prefetched x for the NEXT iteration of this stream
    f32x4 d[4];              // current activations (feature-spread, D-layout)
    short8 bhHi[2], bhLo[2]; // staged B-frags
    f32x4 d3;                // layer-3 output
};

static __device__ __forceinline__ void ph_l1(TState& t, const Frag2& bx, const Frag2* w1f) {
#pragma unroll
    for (int mt = 0; mt < 4; ++mt) {
        f32x4 d = mfma16(w1f[mt].hi, bx.hi, zero4());
        d = mfma16(w1f[mt].hi, bx.lo, d);
        d = mfma16(w1f[mt].lo, bx.hi, d);
        t.d[mt] = d;
    }
}

static __device__ __forceinline__ void ph_l2(TState& t, const Frag2 (*w2f)[2]) {
#pragma unroll
    for (int mt = 0; mt < 4; ++mt) {
        f32x4 d = mfma16(w2f[mt][0].hi, t.bhHi[0], zero4());
        d = mfma16(w2f[mt][0].hi, t.bhLo[0], d);
        d = mfma16(w2f[mt][0].lo, t.bhHi[0], d);
        d = mfma16(w2f[mt][1].hi, t.bhHi[1], d);
        d = mfma16(w2f[mt][1].hi, t.bhLo[1], d);
        d = mfma16(w2f[mt][1].lo, t.bhHi[1], d);
        t.d[mt] = d;
    }
}

static __device__ __forceinline__ void ph_l3(TState& t, const Frag2* w3f) {
    f32x4 a = mfma16(w3f[0].hi, t.bhHi[0], zero4());
    a = mfma16(w3f[0].hi, t.bhLo[0], a);
    a = mfma16(w3f[0].lo, t.bhHi[0], a);
    f32x4 b = mfma16(w3f[1].hi, t.bhHi[1], zero4());
    b = mfma16(w3f[1].hi, t.bhLo[1], b);
    b = mfma16(w3f[1].lo, t.bhHi[1], b);
#pragma unroll
    for (int r = 0; r < 4; ++r) t.d3[r] = a[r] + b[r];
}

// PB<0: no bias add (layer 1 bias is folded into W1's k=24 column)
template<int PB, int PG, int PBE>
static __device__ __forceinline__ void ph_ln_silu(TState& t, const float* sP, int q) {
    float s = 0.f, s2 = 0.f;
#pragma unroll
    for (int mt = 0; mt < 4; ++mt) {
        if (PB >= 0) {
            const f32x4 bv = *(const f32x4*)(sP + PB + mt * 16 + q * 4);
#pragma unroll
            for (int r = 0; r < 4; ++r) t.d[mt][r] += bv[r];
        }
#pragma unroll
        for (int r = 0; r < 4; ++r) { float v = t.d[mt][r]; s += v; s2 = fmaf(v, v, s2); }
    }
    s = red4(s); s2 = red4(s2);
    const float mu = s * (1.f / 64.f);
    const float var = s2 * (1.f / 64.f) - mu * mu;
    const float inv = __builtin_amdgcn_rsqf(var + 1e-5f);
    const float cns = -mu * inv;
#pragma unroll
    for (int mt = 0; mt < 4; ++mt) {
        const f32x4 gv  = *(const f32x4*)(sP + PG  + mt * 16 + q * 4);
        const f32x4 bev = *(const f32x4*)(sP + PBE + mt * 16 + q * 4);
#pragma unroll
        for (int r = 0; r < 4; ++r) {
            float tt = fmaf(t.d[mt][r], inv, cns);
            float v  = fmaf(tt, gv[r], bev[r]);
            t.d[mt][r] = v * __builtin_amdgcn_rcpf(1.f + __expf(-v));
        }
    }
}

static __device__ __forceinline__ void ph_stage(TState& t, unsigned char* sHi, unsigned char* sLo,
                                                u32 crow, u32 ch, int q) {
#pragma unroll
    for (int mt = 0; mt < 4; ++mt) {
        u32x2 hi, lo;
        split4(t.d[mt], hi, lo);
        u32 off = crow + ((((u32)(mt * 2 + (q >> 1))) ^ ch) << 4) + (u32)((q & 1) * 8);
        *(u32x2*)(sHi + off) = hi;
        *(u32x2*)(sLo + off) = lo;
    }
#pragma unroll
    for (int kk = 0; kk < 2; ++kk) {
        u32 roff = crow + ((((u32)(kk * 4 + q)) ^ ch) << 4);
        t.bhHi[kk] = *(const short8*)(sHi + roff);
        t.bhLo[kk] = *(const short8*)(sLo + roff);
    }
}

static __device__ __forceinline__ void ph_out(TState& t, const float* sP, int q, int c, int lane,
                                              unsigned char* ob, float* out, int tile, bool valid,
                                              int oc0, int of0, int oc1, int of1) {
    const f32x4 b3v  = *(const f32x4*)(sP + 384 + q * 4);
    const f32x4 g3v  = *(const f32x4*)(sP + 400 + q * 4);
    const f32x4 be3v = *(const f32x4*)(sP + 416 + q * 4);
    f32x4 d3 = t.d3;
    float s = 0.f, s2 = 0.f;
#pragma unroll
    for (int r = 0; r < 4; ++r) {
        float v = d3[r] + b3v[r];
        d3[r] = v;
        const bool ok = (q * 4 + r) < 7;
        if (ok) { s += v; s2 = fmaf(v, v, s2); }
    }
    s = red4(s); s2 = red4(s2);
    const float mu = s * (1.f / 7.f);
    const float var = s2 * (1.f / 7.f) - mu * mu;
    const float inv = __builtin_amdgcn_rsqf(var + 1e-5f);
    const float cns = -mu * inv;

    float z[4]; float mx = -1e30f;
#pragma unroll
    for (int r = 0; r < 4; ++r) {
        z[r] = fmaf(fmaf(d3[r], inv, cns), g3v[r], be3v[r]);
        const bool ok = (q * 4 + r) < 7;
        if (ok) mx = fmaxf(mx, z[r]);
    }
    mx = redmax4(mx);
    float es = 0.f; float e[4];
#pragma unroll
    for (int r = 0; r < 4; ++r) {
        const bool ok = (q * 4 + r) < 7;
        e[r] = ok ? __expf(z[r] - mx) : 0.f;
        es += e[r];
    }
    es = red4(es);
    const float rs = __builtin_amdgcn_rcpf(es);

    if (q == 0) {
        f32x4 v = {e[0] * rs, e[1] * rs, e[2] * rs, e[3] * rs};
        *(f32x4*)(ob + c * 48) = v;
    } else if (q == 1) {
        f32x2 v = {e[0] * rs, e[1] * rs};
        *(f32x2*)(ob + c * 48 + 16) = v;
        *(float*)(ob + c * 48 + 24) = e[2] * rs;
    }
    if (valid) {
        float* outp = out + (size_t)tile * 112;
        outp[lane] = *(const float*)(ob + oc0 * 48 + of0 * 4);
        if (lane < 48) outp[64 + lane] = *(const float*)(ob + oc1 * 48 + of1 * 4);
    }
}

__global__ __launch_bounds__(BLOCK, 2) void mlp_mfma2_kernel(
    const float* __restrict__ x,
    const float* __restrict__ w1, const float* __restrict__ b1,
    const float* __restrict__ g1, const float* __restrict__ be1,
    const float* __restrict__ w2, const float* __restrict__ b2,
    const float* __restrict__ g2, const float* __restrict__ be2,
    const float* __restrict__ w3, const float* __restrict__ b3,
    const float* __restrict__ g3, const float* __restrict__ be3,
    float* __restrict__ out, int ntiles)
{
    // Per wave: two independent tile streams -> 2 x (2KB hi + 2KB lo) strips + 2 x 768B repack.
    __shared__ __align__(16) unsigned char smem[WPB * (2 * 4096 + 2 * 768)];
    __shared__ __align__(16) float sP[6 * 64 + 3 * 16];

    const int tid = threadIdx.x;
    const int lane = tid & 63;
    const int wib  = tid >> 6;
    const int c = lane & 15;   // batch col within tile
    const int q = lane >> 4;   // k-group (8 elems each)

    if (tid < 64) {
        sP[        tid] = b1[tid];  sP[ 64 + tid] = g1[tid];  sP[128 + tid] = be1[tid];
        sP[192 + tid] = b2[tid];    sP[256 + tid] = g2[tid];  sP[320 + tid] = be2[tid];
    }
    if (tid < 16) {
        const bool ok = tid < 7;
        sP[384 + tid] = ok ? b3[tid]  : 0.f;
        sP[400 + tid] = ok ? g3[tid]  : 0.f;
        sP[416 + tid] = ok ? be3[tid] : 0.f;
    }

    unsigned char* wb   = smem + wib * (2 * 4096 + 2 * 768);
    unsigned char* sHiA = wb;
    unsigned char* sLoA = wb + 2048;
    unsigned char* sHiB = wb + 4096;
    unsigned char* sLoB = wb + 6144;
    unsigned char* obA  = wb + 8192;
    unsigned char* obB  = wb + 8960;

    const u32 crow = (u32)c * 128u;
    const u32 ch   = (u32)(c & 7);

    // ---- preload weight hi/lo frags (live in AGPR/VGPR for the whole kernel) ----
    Frag2 w1f[4];              // W1[64,24] pad K->32; k=24 column carries b1 (bias fold)
#pragma unroll
    for (int mt = 0; mt < 4; ++mt) {
        if (q < 3) {
            w1f[mt] = wfrag(w1 + (mt * 16 + c) * 24 + q * 8);
        } else {
            float s = b1[mt * 16 + c];
            f32x4 a = {s, 0.f, 0.f, 0.f};
            w1f[mt] = split8(a, zero4());
        }
    }
    Frag2 w2f[4][2];           // W2[64,64]
#pragma unroll
    for (int mt = 0; mt < 4; ++mt)
#pragma unroll
        for (int kk = 0; kk < 2; ++kk)
            w2f[mt][kk] = wfrag(w2 + (mt * 16 + c) * 64 + kk * 32 + q * 8);
    Frag2 w3f[2];              // W3[7,64]: rows c<7 valid, rest zero
#pragma unroll
    for (int kk = 0; kk < 2; ++kk) {
        if (c < 7) w3f[kk] = wfrag(w3 + c * 64 + kk * 32 + q * 8);
        else       { w3f[kk].hi = mk_frag(0,0,0,0); w3f[kk].lo = mk_frag(0,0,0,0); }
    }

    __syncthreads();   // sP ready

    // output repack lane mapping
    const int oc0 = lane / 7, of0 = lane - oc0 * 7;
    const int i1 = lane + 64;
    const int oc1 = i1 / 7, of1 = i1 - oc1 * 7;

    const int wid = blockIdx.x * WPB + wib;
    const int ts  = gridDim.x * WPB;

    TState A, B;
    A.xa = zero4(); A.xb = zero4(); B.xa = zero4(); B.xb = zero4();
    {
        const int t0 = wid, t1 = wid + ts;
        if (t0 < ntiles && q < 3) {
            const float* xp = x + ((size_t)t0 * 16 + c) * 24 + q * 8;
            A.xa = *(const f32x4*)xp; A.xb = *(const f32x4*)(xp + 4);
        }
        if (t1 < ntiles && q < 3) {
            const float* xp = x + ((size_t)t1 * 16 + c) * 24 + q * 8;
            B.xa = *(const f32x4*)xp; B.xb = *(const f32x4*)(xp + 4);
        }
        if (q == 3) { A.xa[0] = 1.0f; B.xa[0] = 1.0f; }   // k=24 bias slot; never overwritten (loads guard q<3)
    }

    for (int tile = wid; tile < ntiles; tile += 2 * ts) {
        // keep LDS param reads inside the loop (stop LICM hoisting -> VGPR blowup)
        asm volatile("" ::: "memory");

        const int tB = tile + ts;
        const bool vB = tB < ntiles;

        Frag2 bxA = split8(A.xa, A.xb);
        Frag2 bxB = split8(B.xa, B.xb);

        // prefetch next pair
        {
            const int tA2 = tile + 2 * ts, tB2 = tile + 3 * ts;
            if (tA2 < ntiles && q < 3) {
                const float* xp = x + ((size_t)tA2 * 16 + c) * 24 + q * 8;
                A.xa = *(const f32x4*)xp; A.xb = *(const f32x4*)(xp + 4);
            }
            if (tB2 < ntiles && q < 3) {
                const float* xp = x + ((size_t)tB2 * 16 + c) * 24 + q * 8;
                B.xa = *(const f32x4*)xp; B.xb = *(const f32x4*)(xp + 4);
            }
        }

        // ---- interleaved phases: A and B are fully independent ----
        ph_l1(A, bxA, w1f);                 ph_l1(B, bxB, w1f);
        ph_ln_silu<-1, 64, 128>(A, sP, q);  ph_ln_silu<-1, 64, 128>(B, sP, q);
        ph_stage(A, sHiA, sLoA, crow, ch, q); ph_stage(B, sHiB, sLoB, crow, ch, q);
        ph_l2(A, w2f);                      ph_l2(B, w2f);
        ph_ln_silu<192, 256, 320>(A, sP, q); ph_ln_silu<192, 256, 320>(B, sP, q);
        ph_stage(A, sHiA, sLoA, crow, ch, q); ph_stage(B, sHiB, sLoB, crow, ch, q);
        ph_l3(A, w3f);                      ph_l3(B, w3f);
        ph_out(A, sP, q, c, lane, obA, out, tile, true, oc0, of0, oc1, of1);
        ph_out(B, sP, q, c, lane, obB, out, tB,   vB,   oc0, of0, oc1, of1);
    }
}

extern "C" void kernel_launch(void* const* d_in, const int* in_sizes, int n_in,
                              void* d_out, int out_size, void* d_ws, size_t ws_size,
                              hipStream_t stream) {
    const float* x   = (const float*)d_in[0];
    const float* w1  = (const float*)d_in[1];
    const float* b1  = (const float*)d_in[2];
    const float* g1  = (const float*)d_in[3];
    const float* be1 = (const float*)d_in[4];
    const float* w2  = (const float*)d_in[5];
    const float* b2  = (const float*)d_in[6];
    const float* g2  = (const float*)d_in[7];
    const float* be2 = (const float*)d_in[8];
    const float* w3  = (const float*)d_in[9];
    const float* b3  = (const float*)d_in[10];
    const float* g3  = (const float*)d_in[11];
    const float* be3 = (const float*)d_in[12];
    float* out = (float*)d_out;

    const int B = in_sizes[0] / 24;
    const int ntiles = B / 16;   // B = 2^21 -> exact
    hipLaunchKernelGGL(mlp_mfma2_kernel, dim3(NBLOCKS), dim3(BLOCK), 0, stream,
                       x, w1, b1, g1, be1, w2, b2, g2, be2, w3, b3, g3, be3,
                       out, ntiles);
}